// Round 9
// baseline (80.247 us; speedup 1.0000x reference)
//
#include <hip/hip_runtime.h>

#define L2E 1.44269504088896340736f

typedef float f32x4 __attribute__((ext_vector_type(4)));
typedef __bf16 bf16x8 __attribute__((ext_vector_type(8)));
typedef __bf16 bf16x4 __attribute__((ext_vector_type(4)));

// D(16x16)=A(16x32)*B(32x16)+C. A: lane l = row(l&15), k=8*(l>>4)+e.
// B: col(l&15), k=8*(l>>4)+e. C/D: col(l&15), row=4*(l>>4)+reg. [m89/m91]
__device__ inline void mfma_bf16(bf16x8 a, bf16x8 b, f32x4& c) {
    c = __builtin_amdgcn_mfma_f32_16x16x32_bf16(a, b, c, 0, 0, 0);
}

// whP layout: whP[b][t=j/64][kh=(j/32)&1][ob=o/16][hi=(j/8)&3][r=o&15][e=j&7]
// per-b size = 131072 elems (256KB).

// ---------------- Kernel 1: Wh = h @ W, e_src, e_dst (unchanged) ----------------
__global__ __launch_bounds__(256, 2)
void k1_wh(const float* __restrict__ h, const float* __restrict__ W,
           const float* __restrict__ a, __bf16* __restrict__ whP,
           float* __restrict__ esrc, float* __restrict__ edst) {
    const int tid  = threadIdx.x;
    const int lane = tid & 63;
    const int w    = tid >> 6;
    const int blk  = blockIdx.x;
    const int r0   = blk * 8;
    const int b    = r0 >> 11;
    const int n0   = r0 & 2047;

    __shared__ float pt_s[8][4][64];
    __shared__ float whs[64][8];

    float wreg[64];
    {
        const float* Wp = W + (size_t)(w * 64) * 64 + lane;
#pragma unroll
        for (int kk = 0; kk < 64; kk++) wreg[kk] = Wp[(size_t)kk * 64];
    }

    const float* hbase = h + (size_t)r0 * 256 + w * 64;
    for (int rr = 0; rr < 8; rr++) {
        const float4* hp = (const float4*)(hbase + rr * 256);
        float acc = 0.f;
#pragma unroll
        for (int q = 0; q < 16; q++) {
            float4 hv = hp[q];
            acc += hv.x * wreg[4 * q + 0];
            acc += hv.y * wreg[4 * q + 1];
            acc += hv.z * wreg[4 * q + 2];
            acc += hv.w * wreg[4 * q + 3];
        }
        pt_s[rr][w][lane] = acc;
    }
    __syncthreads();

    const float a1 = a[lane];
    const float a2 = a[64 + lane];
#pragma unroll
    for (int rq = 0; rq < 2; rq++) {
        const int rr = w * 2 + rq;
        float v = pt_s[rr][0][lane] + pt_s[rr][1][lane] +
                  pt_s[rr][2][lane] + pt_s[rr][3][lane];
        whs[lane][rr] = v;
        float e1 = v * a1, e2 = v * a2;
#pragma unroll
        for (int d = 1; d < 64; d <<= 1) {
            e1 += __shfl_xor(e1, d);
            e2 += __shfl_xor(e2, d);
        }
        if (lane == 0) { esrc[r0 + rr] = e1; edst[r0 + rr] = e2; }
    }
    __syncthreads();

    if (tid < 128) {
        const int o  = tid >> 1, hf = (tid & 1) * 4;
        float4 v = *(const float4*)&whs[o][hf];
        bf16x4 bv = { (__bf16)v.x, (__bf16)v.y, (__bf16)v.z, (__bf16)v.w };
        const int t   = n0 >> 6;
        const int kh  = (n0 >> 5) & 1;
        const int hi2 = (n0 >> 3) & 3;
        const int ob  = o >> 4;
        const int rr  = o & 15;
        const size_t flat =
            ((((size_t)(b * 32 + t) * 2 + kh) * 4 + ob) * 4 + hi2) * 128 +
            rr * 8 + hf;
        *(bf16x4*)(whP + flat) = bv;
    }
}

// ---------------- Kernel 2: 32-row blocks, XCD-pinned b, fixed-max attention ----------------
// Block: 32 i-rows, 4 waves = j-quarters (8 tiles of 64). Each wave computes
// TWO 16-row halves sharing the same B-fragments -> whP traffic halves.
// b = blk&7 pins each batch to one XCD -> whP[b] (256KB) L2-resident.
// Masks preamble-built via ballot into LDS. Deterministic 2-stage merge.
// NOTE: mask dwords MUST be pre-shifted by hi*8 before bit extraction
// (r8 bug: missing shift -> 3/4 of columns wrongly masked).
__global__ __launch_bounds__(256, 3)
void k2_attn(const int* __restrict__ adj, const __bf16* __restrict__ whP,
             const float* __restrict__ esrc, const float* __restrict__ edst,
             float* __restrict__ out) {
    const int tid  = threadIdx.x;
    const int lane = tid & 63;
    const int jg   = tid >> 6;          // wave: preamble rows / j-quarter
    const int blk  = blockIdx.x;        // 0..511
    const int b    = blk & 7;           // XCD pin
    const int i0   = (blk >> 3) * 32;
    const int r    = lane & 15;
    const int hi   = lane >> 4;         // 0..3

    __shared__ float edst_s[2048];
    __shared__ float esrc_s[32];
    __shared__ float red_s[4];
    __shared__ unsigned msk_s[32][66];      // pad 66: conflict-free
    __shared__ float mrg_s[2][8][4][64];    // 16 KB, [region][slot][reg][lane]
    __shared__ float mrgl_s[2][2][16];

    // ---- preamble A: mask build (8 rows per wave) ----
#pragma unroll
    for (int rr = 0; rr < 8; rr++) {
        const int row = jg * 8 + rr;
        const int* arow = adj + (size_t)(b * 2048 + i0 + row) * 2048 + lane;
        int av[32];
#pragma unroll
        for (int k = 0; k < 32; k++) av[k] = arow[k * 64];
        unsigned myd = 0u;
#pragma unroll
        for (int k = 0; k < 32; k++) {
            unsigned long long bal = __ballot(av[k] > 0);
            if ((lane >> 1) == k)
                myd = (lane & 1) ? (unsigned)(bal >> 32) : (unsigned)bal;
        }
        msk_s[row][lane] = myd;
    }

    // ---- preamble B: edst stage + block max, esrc ----
    float mymax = -3.0e38f;
#pragma unroll
    for (int q = 0; q < 2; q++) {
        float4 v = *(const float4*)&edst[b * 2048 + q * 1024 + tid * 4];
        *(float4*)&edst_s[q * 1024 + tid * 4] = v;
        mymax = fmaxf(fmaxf(mymax, v.x), fmaxf(v.y, fmaxf(v.z, v.w)));
    }
#pragma unroll
    for (int d = 1; d < 64; d <<= 1) mymax = fmaxf(mymax, __shfl_xor(mymax, d));
    if (lane == 0) red_s[jg] = mymax;
    if (tid < 32) esrc_s[tid] = esrc[b * 2048 + i0 + tid];
    __syncthreads();

    const float maxed = fmaxf(fmaxf(red_s[0], red_s[1]), fmaxf(red_s[2], red_s[3]));
    const float es0 = esrc_s[r];
    const float es1 = esrc_s[16 + r];
    float M0 = es0 + maxed; M0 = fmaxf(M0, 0.2f * M0);   // lrelu upper bound
    float M1 = es1 + maxed; M1 = fmaxf(M1, 0.2f * M1);
    const float Mc0 = M0 * L2E;
    const float Mc1 = M1 * L2E;

    const int jbase = jg * 512;
    const __bf16* wbase = whP + (size_t)b * 131072 +
                          (size_t)(jg * 8) * 4096 + lane * 8;

    f32x4 laccA = {0,0,0,0}, laccB = {0,0,0,0};
    f32x4 accA0={0,0,0,0}, accA1={0,0,0,0}, accA2={0,0,0,0}, accA3={0,0,0,0};
    f32x4 accB0={0,0,0,0}, accB1={0,0,0,0}, accB2={0,0,0,0}, accB3={0,0,0,0};

#define PB(ES, MC, E, bits, sh, base)                                         \
    {                                                                         \
        const unsigned bb = (bits) >> (sh);                                   \
        float v;                                                              \
        v = (ES) + E.x; v = fmaxf(v, 0.2f * v);                               \
        p[base + 0] = (bb & 1u) ? exp2f(__builtin_fmaf(v, L2E, -(MC))) : 0.f; \
        v = (ES) + E.y; v = fmaxf(v, 0.2f * v);                               \
        p[base + 1] = (bb & 2u) ? exp2f(__builtin_fmaf(v, L2E, -(MC))) : 0.f; \
        v = (ES) + E.z; v = fmaxf(v, 0.2f * v);                               \
        p[base + 2] = (bb & 4u) ? exp2f(__builtin_fmaf(v, L2E, -(MC))) : 0.f; \
        v = (ES) + E.w; v = fmaxf(v, 0.2f * v);                               \
        p[base + 3] = (bb & 8u) ? exp2f(__builtin_fmaf(v, L2E, -(MC))) : 0.f; \
    }

    for (int tl = 0; tl < 8; ++tl) {
        const int jt = tl * 64;
        const uint2 mA = *(const uint2*)&msk_s[r][jg * 16 + tl * 2];
        const uint2 mB = *(const uint2*)&msk_s[16 + r][jg * 16 + tl * 2];
        // pre-shift by hi*8: lane (r,hi) owns cols {8hi..8hi+7, 32+8hi..+7}
        const unsigned aLo = mA.x >> (hi * 8);
        const unsigned aHi = mA.y >> (hi * 8);
        const unsigned bLo = mB.x >> (hi * 8);
        const unsigned bHi = mB.y >> (hi * 8);
        const __bf16* wb = wbase + (size_t)tl * 4096;
        bf16x8 B00 = *(const bf16x8*)(wb);              // kh0 ob0
        bf16x8 B01 = *(const bf16x8*)(wb + 512);        // kh0 ob1
        bf16x8 B02 = *(const bf16x8*)(wb + 1024);       // kh0 ob2
        bf16x8 B03 = *(const bf16x8*)(wb + 1536);       // kh0 ob3
        bf16x8 B10 = *(const bf16x8*)(wb + 2048);       // kh1 ob0
        bf16x8 B11 = *(const bf16x8*)(wb + 2560);       // kh1 ob1
        bf16x8 B12 = *(const bf16x8*)(wb + 3072);       // kh1 ob2
        bf16x8 B13 = *(const bf16x8*)(wb + 3584);       // kh1 ob3
        float4 e0 = *(const float4*)&edst_s[jbase + jt + hi * 8];
        float4 e1 = *(const float4*)&edst_s[jbase + jt + hi * 8 + 4];
        float4 e2 = *(const float4*)&edst_s[jbase + jt + 32 + hi * 8];
        float4 e3 = *(const float4*)&edst_s[jbase + jt + 32 + hi * 8 + 4];
        float p[16];
        // ---- half A (rows i0 .. i0+15) ----
        PB(es0, Mc0, e0, aLo, 0, 0)  PB(es0, Mc0, e1, aLo, 4, 4)
        PB(es0, Mc0, e2, aHi, 0, 8)  PB(es0, Mc0, e3, aHi, 4, 12)
        laccA[0] += p[0] + p[4] + p[8]  + p[12];
        laccA[1] += p[1] + p[5] + p[9]  + p[13];
        laccA[2] += p[2] + p[6] + p[10] + p[14];
        laccA[3] += p[3] + p[7] + p[11] + p[15];
        bf16x8 paA0, paA1;
#pragma unroll
        for (int e = 0; e < 8; e++) {
            paA0[e] = (__bf16)p[e];
            paA1[e] = (__bf16)p[e + 8];
        }
        // ---- half B (rows i0+16 .. i0+31) ----
        PB(es1, Mc1, e0, bLo, 0, 0)  PB(es1, Mc1, e1, bLo, 4, 4)
        PB(es1, Mc1, e2, bHi, 0, 8)  PB(es1, Mc1, e3, bHi, 4, 12)
        laccB[0] += p[0] + p[4] + p[8]  + p[12];
        laccB[1] += p[1] + p[5] + p[9]  + p[13];
        laccB[2] += p[2] + p[6] + p[10] + p[14];
        laccB[3] += p[3] + p[7] + p[11] + p[15];
        bf16x8 paB0, paB1;
#pragma unroll
        for (int e = 0; e < 8; e++) {
            paB0[e] = (__bf16)p[e];
            paB1[e] = (__bf16)p[e + 8];
        }
        // ---- 16 MFMAs; B-frags shared across both halves ----
        mfma_bf16(paA0, B00, accA0); mfma_bf16(paA1, B10, accA0);
        mfma_bf16(paA0, B01, accA1); mfma_bf16(paA1, B11, accA1);
        mfma_bf16(paA0, B02, accA2); mfma_bf16(paA1, B12, accA2);
        mfma_bf16(paA0, B03, accA3); mfma_bf16(paA1, B13, accA3);
        mfma_bf16(paB0, B00, accB0); mfma_bf16(paB1, B10, accB0);
        mfma_bf16(paB0, B01, accB1); mfma_bf16(paB1, B11, accB1);
        mfma_bf16(paB0, B02, accB2); mfma_bf16(paB1, B12, accB2);
        mfma_bf16(paB0, B03, accB3); mfma_bf16(paB1, B13, accB3);
    }
#undef PB

    float lsA = laccA[0] + laccA[1] + laccA[2] + laccA[3];
    lsA += __shfl_xor(lsA, 16); lsA += __shfl_xor(lsA, 32);
    float lsB = laccB[0] + laccB[1] + laccB[2] + laccB[3];
    lsB += __shfl_xor(lsB, 16); lsB += __shfl_xor(lsB, 32);

#define ST_ACC(Rg)                                                            \
    {                                                                         \
        _Pragma("unroll")                                                     \
        for (int reg = 0; reg < 4; reg++) {                                   \
            mrg_s[Rg][0][reg][lane] = accA0[reg];                             \
            mrg_s[Rg][1][reg][lane] = accA1[reg];                             \
            mrg_s[Rg][2][reg][lane] = accA2[reg];                             \
            mrg_s[Rg][3][reg][lane] = accA3[reg];                             \
            mrg_s[Rg][4][reg][lane] = accB0[reg];                             \
            mrg_s[Rg][5][reg][lane] = accB1[reg];                             \
            mrg_s[Rg][6][reg][lane] = accB2[reg];                             \
            mrg_s[Rg][7][reg][lane] = accB3[reg];                             \
        }                                                                     \
        if (lane < 16) { mrgl_s[Rg][0][r] = lsA; mrgl_s[Rg][1][r] = lsB; }    \
    }

#define ADD_ACC(Rg)                                                           \
    {                                                                         \
        _Pragma("unroll")                                                     \
        for (int reg = 0; reg < 4; reg++) {                                   \
            accA0[reg] += mrg_s[Rg][0][reg][lane];                            \
            accA1[reg] += mrg_s[Rg][1][reg][lane];                            \
            accA2[reg] += mrg_s[Rg][2][reg][lane];                            \
            accA3[reg] += mrg_s[Rg][3][reg][lane];                            \
            accB0[reg] += mrg_s[Rg][4][reg][lane];                            \
            accB1[reg] += mrg_s[Rg][5][reg][lane];                            \
            accB2[reg] += mrg_s[Rg][6][reg][lane];                            \
            accB3[reg] += mrg_s[Rg][7][reg][lane];                            \
        }                                                                     \
        lsA += mrgl_s[Rg][0][r]; lsB += mrgl_s[Rg][1][r];                     \
    }

    // deterministic 2-stage merge: ((0+1) + (2+3))
    if (jg == 1) ST_ACC(0)
    if (jg == 3) ST_ACC(1)
    __syncthreads();
    if (jg == 0) ADD_ACC(0)
    if (jg == 2) ADD_ACC(1)
    __syncthreads();
    if (jg == 2) ST_ACC(0)
    __syncthreads();
    if (jg == 0) {
        ADD_ACC(0)
#pragma unroll
        for (int reg = 0; reg < 4; reg++) {
            const float LA  = __shfl(lsA, hi * 4 + reg);
            const float LB  = __shfl(lsB, hi * 4 + reg);
            const float iLA = 1.0f / LA;
            const float iLB = 1.0f / LB;
            float* opA = out + (size_t)(b * 2048 + i0 + hi * 4 + reg) * 64 + r;
            float* opB = opA + 16 * 64;
            float v;
            v = accA0[reg] * iLA; v = v > 0.f ? v : expm1f(v); opA[0]  = v;
            v = accA1[reg] * iLA; v = v > 0.f ? v : expm1f(v); opA[16] = v;
            v = accA2[reg] * iLA; v = v > 0.f ? v : expm1f(v); opA[32] = v;
            v = accA3[reg] * iLA; v = v > 0.f ? v : expm1f(v); opA[48] = v;
            v = accB0[reg] * iLB; v = v > 0.f ? v : expm1f(v); opB[0]  = v;
            v = accB1[reg] * iLB; v = v > 0.f ? v : expm1f(v); opB[16] = v;
            v = accB2[reg] * iLB; v = v > 0.f ? v : expm1f(v); opB[32] = v;
            v = accB3[reg] * iLB; v = v > 0.f ? v : expm1f(v); opB[48] = v;
        }
    }
#undef ST_ACC
#undef ADD_ACC
}

extern "C" void kernel_launch(void* const* d_in, const int* in_sizes, int n_in,
                              void* d_out, int out_size, void* d_ws, size_t ws_size,
                              hipStream_t stream) {
    const float* h   = (const float*)d_in[0];
    const int*   adj = (const int*)d_in[1];
    const float* W   = (const float*)d_in[2];
    const float* a   = (const float*)d_in[3];
    float* out = (float*)d_out;

    __bf16* whP  = (__bf16*)d_ws;                                  // 2 MB
    float*  esrc = (float*)((char*)d_ws + (size_t)8 * 131072 * 2);
    float*  edst = esrc + 8 * 2048;

    hipLaunchKernelGGL(k1_wh, dim3(2048), dim3(256), 0, stream,
                       h, W, a, whP, esrc, edst);
    hipLaunchKernelGGL(k2_attn, dim3(512), dim3(256), 0, stream,
                       adj, whP, esrc, edst, out);
}

// Round 10
// 73.055 us; speedup vs baseline: 1.0984x; 1.0984x over previous
//
#include <hip/hip_runtime.h>

#define L2E 1.44269504088896340736f

typedef float f32x4 __attribute__((ext_vector_type(4)));
typedef __bf16 bf16x8 __attribute__((ext_vector_type(8)));
typedef __bf16 bf16x4 __attribute__((ext_vector_type(4)));

__device__ inline void mfma_bf16(bf16x8 a, bf16x8 b, f32x4& c) {
    c = __builtin_amdgcn_mfma_f32_16x16x32_bf16(a, b, c, 0, 0, 0);
}

// ws layout (bytes):
//   [0)        whP   8*131072 bf16 = 2097152
//   [2097152)  esrc  8*2048 f32    = 65536
//   [2162688)  edst  8*2048 f32    = 65536
//   [2228224)  num   8*2048*64 f32 = 4194304
//   [6422528)  den   8*2048 f32    = 65536   (num+den zeroed by k1)
#define WS_ESRC 2097152
#define WS_EDST 2162688
#define WS_NUM  2228224
#define WS_DEN  6422528

// whP layout: whP[b][t=j/64][kh=(j/32)&1][ob=o/16][hi=(j/8)&3][r=o&15][e=j&7]

// ---------------- Kernel 1: Wh = h @ W, e_src, e_dst (+ zero num/den) ----------------
__global__ __launch_bounds__(256, 2)
void k1_wh(const float* __restrict__ h, const float* __restrict__ W,
           const float* __restrict__ a, __bf16* __restrict__ whP,
           float* __restrict__ esrc, float* __restrict__ edst,
           float* __restrict__ numden) {
    const int tid  = threadIdx.x;
    const int lane = tid & 63;
    const int w    = tid >> 6;
    const int blk  = blockIdx.x;
    const int r0   = blk * 8;
    const int b    = r0 >> 11;
    const int n0   = r0 & 2047;

    // zero num+den: 1064960 floats = 2048 blocks x 130 float4 (exact)
    if (tid < 130) {
        const int zi = blk * 130 + tid;
        *(float4*)&numden[zi * 4] = make_float4(0.f, 0.f, 0.f, 0.f);
    }

    __shared__ float pt_s[8][4][64];
    __shared__ float whs[64][8];

    float wreg[64];
    {
        const float* Wp = W + (size_t)(w * 64) * 64 + lane;
#pragma unroll
        for (int kk = 0; kk < 64; kk++) wreg[kk] = Wp[(size_t)kk * 64];
    }

    const float* hbase = h + (size_t)r0 * 256 + w * 64;
    for (int rr = 0; rr < 8; rr++) {
        const float4* hp = (const float4*)(hbase + rr * 256);
        float acc = 0.f;
#pragma unroll
        for (int q = 0; q < 16; q++) {
            float4 hv = hp[q];
            acc += hv.x * wreg[4 * q + 0];
            acc += hv.y * wreg[4 * q + 1];
            acc += hv.z * wreg[4 * q + 2];
            acc += hv.w * wreg[4 * q + 3];
        }
        pt_s[rr][w][lane] = acc;
    }
    __syncthreads();

    const float a1 = a[lane];
    const float a2 = a[64 + lane];
#pragma unroll
    for (int rq = 0; rq < 2; rq++) {
        const int rr = w * 2 + rq;
        float v = pt_s[rr][0][lane] + pt_s[rr][1][lane] +
                  pt_s[rr][2][lane] + pt_s[rr][3][lane];
        whs[lane][rr] = v;
        float e1 = v * a1, e2 = v * a2;
#pragma unroll
        for (int d = 1; d < 64; d <<= 1) {
            e1 += __shfl_xor(e1, d);
            e2 += __shfl_xor(e2, d);
        }
        if (lane == 0) { esrc[r0 + rr] = e1; edst[r0 + rr] = e2; }
    }
    __syncthreads();

    if (tid < 128) {
        const int o  = tid >> 1, hf = (tid & 1) * 4;
        float4 v = *(const float4*)&whs[o][hf];
        bf16x4 bv = { (__bf16)v.x, (__bf16)v.y, (__bf16)v.z, (__bf16)v.w };
        const int t   = n0 >> 6;
        const int kh  = (n0 >> 5) & 1;
        const int hi2 = (n0 >> 3) & 3;
        const int ob  = o >> 4;
        const int rr  = o & 15;
        const size_t flat =
            ((((size_t)(b * 32 + t) * 2 + kh) * 4 + ob) * 4 + hi2) * 128 +
            rr * 8 + hf;
        *(bf16x4*)(whP + flat) = bv;
    }
}

// ---------------- Kernel 2: LDS-whP, in-loop ballot adj, fixed-max, atomic merge ----------------
// Block: 512 thr = 8 waves; covers 128 rows x 512 cols (jq quarter).
// whP slice (64KB) staged to LDS once; per tile: 16 coalesced adj dwords
// + ballot (r6-proven), 8 ds_read_b128 B-frags, exp2, 8 MFMA. Partial
// (num,den) merged across the 4 jq blocks via atomicAdd; k3 finalizes.
__global__ __launch_bounds__(512, 4)
void k2_attn(const int* __restrict__ adj, const __bf16* __restrict__ whP,
             const float* __restrict__ esrc, const float* __restrict__ edst,
             float* __restrict__ num, float* __restrict__ den) {
    const int tid  = threadIdx.x;
    const int lane = tid & 63;
    const int w    = tid >> 6;          // wave 0..7: rows i0+16w..+15
    const int blk  = blockIdx.x;        // 0..511
    const int b    = blk & 7;           // XCD pin
    const int t2   = blk >> 3;
    const int jq   = t2 & 3;            // j-quarter
    const int rg   = t2 >> 2;           // 0..15
    const int i0   = rg * 128;
    const int r    = lane & 15;
    const int hi   = lane >> 4;         // 0..3

    __shared__ __align__(16) __bf16 whp_s[32768];   // 64 KB
    __shared__ float edst_s[512];
    __shared__ float esrc_s[128];
    __shared__ float red_s[8];

    // ---- stage whP slice: 8 x (512 thr x 16B) = 64 KB ----
    const __bf16* wsrc = whP + (size_t)b * 131072 + (size_t)jq * 32768;
#pragma unroll
    for (int it = 0; it < 8; it++) {
        const int idx = it * 512 + tid;
        *(bf16x8*)&whp_s[idx * 8] = *(const bf16x8*)&wsrc[(size_t)idx * 8];
    }
    // ---- global max over full edst row of this batch ----
    {
        float4 v = *(const float4*)&edst[b * 2048 + tid * 4];
        float mymax = fmaxf(fmaxf(v.x, v.y), fmaxf(v.z, v.w));
#pragma unroll
        for (int d = 1; d < 64; d <<= 1)
            mymax = fmaxf(mymax, __shfl_xor(mymax, d));
        if (lane == 0) red_s[w] = mymax;
    }
    edst_s[tid] = edst[b * 2048 + jq * 512 + tid];
    if (tid < 128) esrc_s[tid] = esrc[b * 2048 + i0 + tid];
    __syncthreads();

    float maxed = red_s[0];
#pragma unroll
    for (int q = 1; q < 8; q++) maxed = fmaxf(maxed, red_s[q]);
    const float es = esrc_s[w * 16 + r];
    float M = es + maxed;
    M = fmaxf(M, 0.2f * M);             // lrelu (monotone) upper bound
    const float Mc = M * L2E;

    const int* arow = adj + (size_t)(b * 2048 + i0 + w * 16) * 2048 +
                      jq * 512 + lane;

    f32x4 lacc = {0.f, 0.f, 0.f, 0.f};
    f32x4 acc0 = {0,0,0,0}, acc1 = {0,0,0,0}, acc2 = {0,0,0,0}, acc3 = {0,0,0,0};

#define PB(E, bits, sh, base)                                                 \
    {                                                                         \
        const unsigned bb = (bits) >> (sh);                                   \
        float v;                                                              \
        v = es + E.x; v = fmaxf(v, 0.2f * v);                                 \
        p[base + 0] = (bb & 1u) ? exp2f(__builtin_fmaf(v, L2E, -Mc)) : 0.f;   \
        v = es + E.y; v = fmaxf(v, 0.2f * v);                                 \
        p[base + 1] = (bb & 2u) ? exp2f(__builtin_fmaf(v, L2E, -Mc)) : 0.f;   \
        v = es + E.z; v = fmaxf(v, 0.2f * v);                                 \
        p[base + 2] = (bb & 4u) ? exp2f(__builtin_fmaf(v, L2E, -Mc)) : 0.f;   \
        v = es + E.w; v = fmaxf(v, 0.2f * v);                                 \
        p[base + 3] = (bb & 8u) ? exp2f(__builtin_fmaf(v, L2E, -Mc)) : 0.f;   \
    }

    for (int tl = 0; tl < 8; ++tl) {
        const int jt = tl * 64;
        // 16 coalesced adj dword loads (issue all -> MLP)
        int av[16];
#pragma unroll
        for (int rr = 0; rr < 16; rr++) av[rr] = arow[(size_t)rr * 2048 + jt];
        // 8 B-frags from LDS (linear, conflict-free b128)
        const __bf16* wb = whp_s + tl * 4096 + lane * 8;
        bf16x8 B00 = *(const bf16x8*)(wb);              // kh0 ob0
        bf16x8 B01 = *(const bf16x8*)(wb + 512);        // kh0 ob1
        bf16x8 B02 = *(const bf16x8*)(wb + 1024);       // kh0 ob2
        bf16x8 B03 = *(const bf16x8*)(wb + 1536);       // kh0 ob3
        bf16x8 B10 = *(const bf16x8*)(wb + 2048);       // kh1 ob0
        bf16x8 B11 = *(const bf16x8*)(wb + 2560);       // kh1 ob1
        bf16x8 B12 = *(const bf16x8*)(wb + 3072);       // kh1 ob2
        bf16x8 B13 = *(const bf16x8*)(wb + 3584);       // kh1 ob3
        // ballots -> my row's mask dwords
        unsigned mlo = 0u, mhi2 = 0u;
#pragma unroll
        for (int rr = 0; rr < 16; rr++) {
            unsigned long long bal = __ballot(av[rr] > 0);
            if (r == rr) { mlo  = (unsigned)bal;
                           mhi2 = (unsigned)(bal >> 32); }
        }
        const unsigned aLo = mlo  >> (hi * 8);   // pre-shift (r8 lesson)
        const unsigned aHi = mhi2 >> (hi * 8);
        // scores -> p
        float4 e0 = *(const float4*)&edst_s[jt + hi * 8];
        float4 e1 = *(const float4*)&edst_s[jt + hi * 8 + 4];
        float4 e2 = *(const float4*)&edst_s[jt + 32 + hi * 8];
        float4 e3 = *(const float4*)&edst_s[jt + 32 + hi * 8 + 4];
        float p[16];
        PB(e0, aLo, 0, 0) PB(e1, aLo, 4, 4) PB(e2, aHi, 0, 8) PB(e3, aHi, 4, 12)
        lacc[0] += p[0] + p[4] + p[8]  + p[12];
        lacc[1] += p[1] + p[5] + p[9]  + p[13];
        lacc[2] += p[2] + p[6] + p[10] + p[14];
        lacc[3] += p[3] + p[7] + p[11] + p[15];
        bf16x8 pa0, pa1;
#pragma unroll
        for (int e = 0; e < 8; e++) {
            pa0[e] = (__bf16)p[e];
            pa1[e] = (__bf16)p[e + 8];
        }
        mfma_bf16(pa0, B00, acc0); mfma_bf16(pa1, B10, acc0);
        mfma_bf16(pa0, B01, acc1); mfma_bf16(pa1, B11, acc1);
        mfma_bf16(pa0, B02, acc2); mfma_bf16(pa1, B12, acc2);
        mfma_bf16(pa0, B03, acc3); mfma_bf16(pa1, B13, acc3);
    }
#undef PB

    // ---- atomic merge: den (per row) + num (16 values/lane) ----
    float lsum = lacc[0] + lacc[1] + lacc[2] + lacc[3];
    lsum += __shfl_xor(lsum, 16);
    lsum += __shfl_xor(lsum, 32);
    const int rowbase = b * 2048 + i0 + w * 16;
    if (lane < 16) atomicAdd(&den[rowbase + r], lsum);
#pragma unroll
    for (int reg = 0; reg < 4; reg++) {
        float* np = num + (size_t)(rowbase + 4 * hi + reg) * 64 + r;
        atomicAdd(np +  0, acc0[reg]);
        atomicAdd(np + 16, acc1[reg]);
        atomicAdd(np + 32, acc2[reg]);
        atomicAdd(np + 48, acc3[reg]);
    }
}

// ---------------- Kernel 3: out = elu(num / den) ----------------
__global__ __launch_bounds__(256, 4)
void k3_fin(const float* __restrict__ num, const float* __restrict__ den,
            float* __restrict__ out) {
    const int i = blockIdx.x * 256 + threadIdx.x;   // float4 index, 0..262143
    float4 n = *(const float4*)&num[(size_t)i * 4];
    const float inv = 1.0f / den[i >> 4];
    float v0 = n.x * inv, v1 = n.y * inv, v2 = n.z * inv, v3 = n.w * inv;
    v0 = v0 > 0.f ? v0 : expm1f(v0);
    v1 = v1 > 0.f ? v1 : expm1f(v1);
    v2 = v2 > 0.f ? v2 : expm1f(v2);
    v3 = v3 > 0.f ? v3 : expm1f(v3);
    *(float4*)&out[(size_t)i * 4] = make_float4(v0, v1, v2, v3);
}

extern "C" void kernel_launch(void* const* d_in, const int* in_sizes, int n_in,
                              void* d_out, int out_size, void* d_ws, size_t ws_size,
                              hipStream_t stream) {
    const float* h   = (const float*)d_in[0];
    const int*   adj = (const int*)d_in[1];
    const float* W   = (const float*)d_in[2];
    const float* a   = (const float*)d_in[3];
    float* out = (float*)d_out;

    char* ws = (char*)d_ws;
    __bf16* whP  = (__bf16*)ws;
    float*  esrc = (float*)(ws + WS_ESRC);
    float*  edst = (float*)(ws + WS_EDST);
    float*  num  = (float*)(ws + WS_NUM);
    float*  den  = (float*)(ws + WS_DEN);

    hipLaunchKernelGGL(k1_wh, dim3(2048), dim3(256), 0, stream,
                       h, W, a, whP, esrc, edst, num);
    hipLaunchKernelGGL(k2_attn, dim3(512), dim3(512), 0, stream,
                       adj, whP, esrc, edst, num, den);
    hipLaunchKernelGGL(k3_fin, dim3(1024), dim3(256), 0, stream,
                       num, den, out);
}